// Round 5
// baseline (888.740 us; speedup 1.0000x reference)
//
#include <hip/hip_runtime.h>

// DerivNet2D fused MLP + forward-mode derivatives, v4.
// A[96 = 3 bands x 32 samples][K=1024] @ W2^T[1024][512], MFMA 32x32x16 bf16.
// BK=128, A double-buffered in LDS; B fragment-major from L2 into regs.
// v4: fine-grained 8-phase kt body — per phase: issue B[ks+1], issue A[ks+1],
// one stage-chunk (2 tanh x 3 bands) for kt+1, then 12 MFMA on prev-phase regs.

#define NXS    65536
#define SB     32
#define NBLK   2048        // NXS / SB
#define KSTEPS 8           // K=1024 / 128

typedef short bh8_t __attribute__((ext_vector_type(8)));    // 8 x bf16
typedef unsigned int u32x4 __attribute__((ext_vector_type(4)));
typedef float fx16_t __attribute__((ext_vector_type(16)));  // 32x32 accum
typedef unsigned int u32;

static __device__ __forceinline__ unsigned short f2bf(float f) {
  u32 u = __builtin_bit_cast(u32, f);
  u += 0x7FFFu + ((u >> 16) & 1u);      // RNE (prep kernel only)
  return (unsigned short)(u >> 16);
}

static __device__ __forceinline__ u32 pkbf(float lo, float hi) {
  u32 r;
  asm("v_cvt_pk_bf16_f32 %0, %1, %2" : "=v"(r) : "v"(lo), "v"(hi));
  return r;
}

static __device__ __forceinline__ float fast_tanh(float h) {
  float e = __expf(2.0f * h);
  return 1.0f - 2.0f / (e + 1.0f);
}

// prep: (a) W2 fp32 [512][1024] -> fragment-major bf16 frags
//   f = ((kblock*16 + nbk)*64 + q*32 + col), 16B each, holding
//   W2[n = nbk*32+col][k = 16*kblock + {4q..4q+3, 8+4q..8+4q+3}].
// (b) W1b[k] = {W1[k][0], W1[k][1], b1[k], 0} packed float4.
__global__ void prep_all(const float* __restrict__ W2, const float* __restrict__ W1,
                         const float* __restrict__ b1, bh8_t* __restrict__ W2pT,
                         float4* __restrict__ W1b) {
  int f = blockIdx.x * 256 + threadIdx.x;      // 0..65535
  int col = f & 31;
  int q   = (f >> 5) & 1;
  int nbk = (f >> 6) & 15;
  int kb  = f >> 10;
  const float* row = W2 + (nbk * 32 + col) * 1024 + kb * 16 + 4 * q;
  float4 lo = *(const float4*)(row);
  float4 hi = *(const float4*)(row + 8);
  bh8_t o;
  o[0] = (short)f2bf(lo.x); o[1] = (short)f2bf(lo.y);
  o[2] = (short)f2bf(lo.z); o[3] = (short)f2bf(lo.w);
  o[4] = (short)f2bf(hi.x); o[5] = (short)f2bf(hi.y);
  o[6] = (short)f2bf(hi.z); o[7] = (short)f2bf(hi.w);
  W2pT[f] = o;
  if (f < 1024) {
    float2 w = *(const float2*)(W1 + 2 * f);
    W1b[f] = make_float4(w.x, w.y, b1[f], 0.0f);
  }
}

__global__ __launch_bounds__(256, 2) void fused_kernel(
    const float* __restrict__ x,  const float4* __restrict__ W1b,
    const float* __restrict__ b2, const float* __restrict__ W3,
    const float* __restrict__ b3, const bh8_t* __restrict__ Bg,
    float* __restrict__ out)
{
  __shared__ __attribute__((aligned(16))) char smem[49152 + 1536];
  const int tid  = threadIdx.x;
  const int lane = tid & 63;
  const int wave = tid >> 6;        // 0..3, owns N cols [128w, 128w+128)
  const int q    = lane >> 5;
  const int col  = lane & 31;
  const int s0   = blockIdx.x * SB;

  // A-gen role: gs = sample, gkb = 16-k block 0..7
  const int gs  = tid & 31;
  const int gkb = tid >> 5;
  const float2 xv = *(const float2*)(x + 2 * (s0 + gs));
  const float x0 = xv.x, x1 = xv.y;
  const int wbase = (gs * 256) | (((gkb << 1) ^ (gs & 7)) << 4);  // gqp=0 unit

  // epilogue constants preloaded (overlaps with prologue latency)
  float b2n[4], w3n[4];
#pragma unroll
  for (int nb = 0; nb < 4; ++nb) {
    int n = wave * 128 + nb * 32 + col;
    b2n[nb] = b2[n];
    w3n[nb] = W3[n];
  }

  fx16_t acc[3][4];
#pragma unroll
  for (int b = 0; b < 3; ++b)
#pragma unroll
    for (int nb = 0; nb < 4; ++nb)
#pragma unroll
      for (int r = 0; r < 16; ++r) acc[b][nb][r] = 0.0f;

  bh8_t Ar[2][3], Br[2][4];
  u32x4 sz, sv0, sv1;          // staging accumulators (one 16B unit x 3 bands)

  auto loadB = [&](int kt, int ks, bh8_t* B) {
    const int fb = ((kt * 8 + ks) * 16 + wave * 4) * 64 + lane;
    B[0] = Bg[fb];
    B[1] = Bg[fb + 64];
    B[2] = Bg[fb + 128];
    B[3] = Bg[fb + 192];
  };
  auto loadA = [&](const char* Ab, int ks, bh8_t* A) {
    const int uoff = (((2 * ks + q) ^ (col & 7)) << 4);
    const char* p = Ab + col * 256 + uoff;
    A[0] = *(const bh8_t*)(p);
    A[1] = *(const bh8_t*)(p + 8192);
    A[2] = *(const bh8_t*)(p + 16384);
  };
  // phase p in 0..7: gqp=p>>2, jp=(p>>1)&1, half=p&1 -> one u32 (2 tanh) per band;
  // unit flush (16B x 3) at p==3 and p==7.
  auto stage_pair = [&](int ktA, char* Ab, int p) {
    const int gqp = p >> 2, jp = (p >> 1) & 1, half = p & 1;
    const int k0 = ktA * 128 + gkb * 16 + gqp * 4 + half * 8 + 2 * jp;
    float4 cA = W1b[k0];
    float4 cB = W1b[k0 + 1];
    float hA = fmaf(x0, cA.x, fmaf(x1, cA.y, cA.z));
    float hB = fmaf(x0, cB.x, fmaf(x1, cB.y, cB.z));
    float zA = fast_tanh(hA), zB = fast_tanh(hB);
    float dA = 1.f - zA * zA, dB = 1.f - zB * zB;
    const int slot = half * 2 + jp;
    sz[slot]  = pkbf(zA, zB);
    sv0[slot] = pkbf(dA * cA.x, dB * cB.x);
    sv1[slot] = pkbf(dA * cA.y, dB * cB.y);
    if ((p & 3) == 3) {
      char* dst = Ab + (wbase ^ (gqp << 4));
      *(u32x4*)(dst)         = sz;
      *(u32x4*)(dst + 8192)  = sv0;
      *(u32x4*)(dst + 16384) = sv1;
    }
  };
  auto mfma12 = [&](const bh8_t* A, const bh8_t* B) {
    __builtin_amdgcn_s_setprio(1);
#pragma unroll
    for (int nb = 0; nb < 4; ++nb) {
      acc[0][nb] = __builtin_amdgcn_mfma_f32_32x32x16_bf16(A[0], B[nb], acc[0][nb], 0, 0, 0);
      acc[1][nb] = __builtin_amdgcn_mfma_f32_32x32x16_bf16(A[1], B[nb], acc[1][nb], 0, 0, 0);
      acc[2][nb] = __builtin_amdgcn_mfma_f32_32x32x16_bf16(A[2], B[nb], acc[2][nb], 0, 0, 0);
    }
    __builtin_amdgcn_s_setprio(0);
  };

  // === prologue: B[0][0] in flight, then full stage of kt=0 ===
  loadB(0, 0, Br[0]);
#pragma unroll
  for (int p = 0; p < 8; ++p) stage_pair(0, smem, p);
  __syncthreads();
  loadA(smem, 0, Ar[0]);

  for (int kt = 0; kt < KSTEPS; ++kt) {
    char* Acur = smem + (kt & 1) * 24576;
    char* Anxt = smem + ((kt + 1) & 1) * 24576;
    const bool more = (kt + 1 < KSTEPS);
#pragma unroll
    for (int ks = 0; ks < 8; ++ks) {
      const int cb = ks & 1, nbuf = cb ^ 1;
      if (ks < 7) {
        loadB(kt, ks + 1, Br[nbuf]);      // longest latency first
        loadA(Acur, ks + 1, Ar[nbuf]);
      } else if (more) {
        loadB(kt + 1, 0, Br[nbuf]);       // crosses the barrier legally
      }
      if (more) stage_pair(kt + 1, Anxt, ks);   // VALU fills the load shadow
      mfma12(Ar[cb], Br[cb]);             // regs issued one phase ago
    }
    __syncthreads();
    if (more) loadA(Anxt, 0, Ar[0]);      // first A of next kt
  }

  // Epilogue: z2 = tanh(h2+b2), d2 = 1-z2^2; weighted reduce over n with W3.
  float* P = (float*)(smem + 49152);   // [3][32 samples][4 waves]
#pragma unroll
  for (int r = 0; r < 16; ++r) {
    const int srow_o = (r & 3) + 8 * (r >> 2) + 4 * q;   // sample 0..31
    float py = 0.f, p1 = 0.f, p2 = 0.f;
#pragma unroll
    for (int nb = 0; nb < 4; ++nb) {
      float z2 = fast_tanh(acc[0][nb][r] + b2n[nb]);
      float d2 = 1.f - z2 * z2;
      py = fmaf(w3n[nb], z2, py);
      p1 = fmaf(w3n[nb] * d2, acc[1][nb][r], p1);
      p2 = fmaf(w3n[nb] * d2, acc[2][nb][r], p2);
    }
#pragma unroll
    for (int m = 1; m < 32; m <<= 1) {
      py += __shfl_xor(py, m, 64);
      p1 += __shfl_xor(p1, m, 64);
      p2 += __shfl_xor(p2, m, 64);
    }
    if (col == 0) {
      P[0 * 128 + srow_o * 4 + wave] = py;
      P[1 * 128 + srow_o * 4 + wave] = p1;
      P[2 * 128 + srow_o * 4 + wave] = p2;
    }
  }
  __syncthreads();
  if (tid < 96) {
    const int v = tid >> 5, s = tid & 31;
    const float* Pv = P + v * 128 + s * 4;
    float sum = Pv[0] + Pv[1] + Pv[2] + Pv[3];
    const int si = s0 + s;
    if (v == 0)      out[si]           = sum + b3[0];  // y
    else if (v == 2) out[NXS + si]     = sum;          // v1 = dydx2
    else             out[2 * NXS + si] = -sum;         // v2 = -dydx1
  }
}

extern "C" void kernel_launch(void* const* d_in, const int* in_sizes, int n_in,
                              void* d_out, int out_size, void* d_ws, size_t ws_size,
                              hipStream_t stream) {
  const float* x  = (const float*)d_in[0];
  const float* W1 = (const float*)d_in[1];
  const float* b1 = (const float*)d_in[2];
  const float* W2 = (const float*)d_in[3];
  const float* b2 = (const float*)d_in[4];
  const float* W3 = (const float*)d_in[5];
  const float* b3 = (const float*)d_in[6];
  bh8_t*  W2pT = (bh8_t*)d_ws;                         // 1 MB fragment-major bf16 W2
  float4* W1b  = (float4*)((char*)d_ws + (1 << 20));   // packed {w0,w1,b1} table

  prep_all<<<256, 256, 0, stream>>>(W2, W1, b1, W2pT, W1b);
  fused_kernel<<<NBLK, 256, 0, stream>>>(
      x, W1b, b2, W3, b3, (const bh8_t*)W2pT, (float*)d_out);
}